// Round 4
// baseline (19887.469 us; speedup 1.0000x reference)
//
#include <hip/hip_runtime.h>
#include <math.h>

#define T_STEPS 4096
#define RES     2048
#define NF      8
#define NR      8
#define K_WG    256      // one WG per CU; WG owns 8 cols (1 per wave)
#define REC_THR 512      // 8 waves
#define RO_THR  256
#define SENTINEL 2.0f    // reachable |x| < 1 strictly (|x|<=0.7|x|+0.3); 2.0 unreachable

// ---------------------------------------------------------------------------
// drive[t][j] = Win[0][j] + sum_f inp[t][f] * Win[1+f][j]
__global__ void k_drive(const float* __restrict__ inp, const float* __restrict__ Win,
                        float* __restrict__ drive) {
    int idx = blockIdx.x * blockDim.x + threadIdx.x;   // [0, T*RES)
    int t = idx >> 11;
    int j = idx & (RES - 1);
    float d = Win[j];
#pragma unroll
    for (int f = 0; f < NF; ++f)
        d += inp[t * NF + f] * Win[(1 + f) * RES + j];
    drive[idx] = d;
}

// ---------------------------------------------------------------------------
// X[0][:] = 0 (valid initial state); X[1..T][:] = SENTINEL (unwritten)
__global__ void k_init(float* __restrict__ X) {
    int tid = threadIdx.x + blockIdx.x * blockDim.x;
    int stride = blockDim.x * gridDim.x;
    const int total = (T_STEPS + 1) * RES;
    for (int i = tid; i < total; i += stride)
        X[i] = (i < RES) ? 0.f : SENTINEL;
}

// ---------------------------------------------------------------------------
// Persistent dataflow recurrence.
//  - 256 WGs x 8 waves. Wave w of WG k owns output column c = 8k+w.
//  - W fragment: 32 floats/lane (rows i*64+lane, one column). Loaded via
//    RELAXED ATOMIC loads: LLVM cannot rematerialize/sink atomic loads into
//    the t-loop — the transformation that defeated register residency in
//    rounds 1-3 (VGPR_Count 84/112/76 all < fragment size; FETCH_SIZE up to
//    1.03 GB from W re-streaming).
//  - Sync: sentinel-in-data. Wave 0 polls global row t (coalesced 256B/load,
//    predicated re-poll), stages into LDS (double-buffered), releases an LDS
//    flag = t+1 (workgroup release). Waves 1-7 spin on the flag (acquire),
//    then ds_read x. 2-buffer safety: wave0 stages row t+2 only after row
//    t+2 is globally complete, which requires this WG's siblings to have
//    finished iteration t+1, hence consumed buffer (t&1) at iteration t.
__global__ __launch_bounds__(REC_THR, 2) void k_recur(
        const float* __restrict__ W, const float* __restrict__ drive,
        float* __restrict__ X) {
    __shared__ float    xs[2][RES];
    __shared__ unsigned flag;        // monotonic: last staged step+1

    const int tid  = threadIdx.x;
    const int wave = tid >> 6;
    const int lane = tid & 63;
    const int c    = blockIdx.x * 8 + wave;   // this wave's output column

    // W fragment: Wr[i] = W[i*64+lane][c]  (32 floats/lane, atomic => pinned)
    float Wr[32];
#pragma unroll
    for (int i = 0; i < 32; ++i)
        Wr[i] = __hip_atomic_load(&W[(size_t)(i * 64 + lane) * RES + c],
                                  __ATOMIC_RELAXED, __HIP_MEMORY_SCOPE_WORKGROUP);

    if (tid == 0) flag = 0;
    __syncthreads();   // one-time init barrier

    float xprev = 0.f;   // lane 0: own column's x_t (x_0 = 0)

    for (int t = 0; t < T_STEPS; ++t) {
        // Independent of x_t: prefetch drive for this wave's column.
        float dr = (lane == 0) ? drive[(size_t)t * RES + c] : 0.f;

        float a = 0.f;
        if (wave == 0) {
            const float* xrow = X + (size_t)t * RES;
            float xv[32];
#pragma unroll
            for (int i = 0; i < 32; ++i)
                xv[i] = __hip_atomic_load(&xrow[i * 64 + lane],
                                          __ATOMIC_RELAXED, __HIP_MEMORY_SCOPE_AGENT);
            for (;;) {
                float m = 0.f;
#pragma unroll
                for (int i = 0; i < 32; ++i)
                    m = fmaxf(m, __builtin_fabsf(xv[i]));
                if (__all(m < 1.5f)) break;
                __builtin_amdgcn_s_sleep(1);
#pragma unroll
                for (int i = 0; i < 32; ++i)
                    if (__builtin_fabsf(xv[i]) > 1.5f)
                        xv[i] = __hip_atomic_load(&xrow[i * 64 + lane],
                                                  __ATOMIC_RELAXED,
                                                  __HIP_MEMORY_SCOPE_AGENT);
            }
            // Stage to LDS (stride-64: 2 lanes/bank = conflict-free).
            float* dst = xs[t & 1];
#pragma unroll
            for (int i = 0; i < 32; ++i)
                dst[i * 64 + lane] = xv[i];
            if (lane == 0)
                __hip_atomic_store(&flag, (unsigned)(t + 1),
                                   __ATOMIC_RELEASE, __HIP_MEMORY_SCOPE_WORKGROUP);
            // Wave 0 computes from its registers directly (skip LDS round-trip).
#pragma unroll
            for (int i = 0; i < 32; ++i)
                a = fmaf(xv[i], Wr[i], a);
        } else {
            while (__hip_atomic_load(&flag, __ATOMIC_ACQUIRE,
                                     __HIP_MEMORY_SCOPE_WORKGROUP) < (unsigned)(t + 1))
                __builtin_amdgcn_s_sleep(1);
            const float* src = xs[t & 1];
#pragma unroll
            for (int i = 0; i < 32; ++i)
                a = fmaf(src[i * 64 + lane], Wr[i], a);
        }

        // 64-lane butterfly: lane 0 ends with the full column sum.
#pragma unroll
        for (int off = 32; off >= 1; off >>= 1)
            a += __shfl_xor(a, off, 64);

        if (lane == 0) {
            float xn = 0.7f * xprev + 0.3f * tanhf(dr + a);
            xprev = xn;
            __hip_atomic_store(&X[(size_t)(t + 1) * RES + c], xn,
                               __ATOMIC_RELAXED, __HIP_MEMORY_SCOPE_AGENT);
        }
    }
}

// ---------------------------------------------------------------------------
// Y[t][r] = Wout[0][r] + sum_f inp[t][f]*Wout[1+f][r] + sum_j X[t+1][j]*Wout[9+j][r]
__global__ void k_readout(const float* __restrict__ inp, const float* __restrict__ Wout,
                          const float* __restrict__ X, float* __restrict__ Y) {
    int t   = blockIdx.x;
    int tid = threadIdx.x;
    int r   = tid & (NR - 1);
    int gph = tid >> 3;                    // 32 groups
    const float* x = X + (size_t)(t + 1) * RES;
    float p = 0.f;
#pragma unroll 4
    for (int m = 0; m < RES / 32; ++m) {
        int j = gph * (RES / 32) + m;
        p += x[j] * Wout[(size_t)(1 + NF + j) * NR + r];
    }
    __shared__ float red[RO_THR];
    red[tid] = p;
    __syncthreads();
    for (int s = RO_THR / 2; s >= NR; s >>= 1) {
        if (tid < s) red[tid] += red[tid + s];
        __syncthreads();
    }
    if (tid < NR) {
        float y = Wout[tid];
#pragma unroll
        for (int f = 0; f < NF; ++f)
            y += inp[t * NF + f] * Wout[(1 + f) * NR + tid];
        Y[t * NR + tid] = y + red[tid];
    }
}

// ---------------------------------------------------------------------------
extern "C" void kernel_launch(void* const* d_in, const int* in_sizes, int n_in,
                              void* d_out, int out_size, void* d_ws, size_t ws_size,
                              hipStream_t stream) {
    const float* inp  = (const float*)d_in[0];   // (T, 8)
    const float* Win  = (const float*)d_in[1];   // (9, 2048)
    const float* W    = (const float*)d_in[2];   // (2048, 2048)
    const float* Wout = (const float*)d_in[3];   // (2057, 8)
    float* Y = (float*)d_out;                    // (T, 8)

    float* drive = (float*)d_ws;                            // 32 MB
    float* X     = drive + (size_t)T_STEPS * RES;           // 32 MB + 8 KB

    k_init<<<2048, 256, 0, stream>>>(X);
    k_drive<<<(T_STEPS * RES) / 256, 256, 0, stream>>>(inp, Win, drive);
    k_recur<<<K_WG, REC_THR, 0, stream>>>(W, drive, X);
    k_readout<<<T_STEPS, RO_THR, 0, stream>>>(inp, Wout, X, Y);
}